// Round 16
// baseline (170.662 us; speedup 1.0000x reference)
//
#include <hip/hip_runtime.h>
#include <hip/hip_bf16.h>

// ModalAttention fused pipeline, MI355X (gfx950).
//
// Math: attn/|global_min| followed by L2-normalize cancels any positive
// per-tensor scale (incl. /sqrt(h)) -> softmax input = s_row/||s_row||_2,
// s = q.k. No global-min reduction needed.
//
// Round 16:
//  - qkv: 256x256 tile (8 waves 2Mx4N, per-wave 128x64, acc[8][4]),
//    2-slot 64KB LDS (128KB, 1 blk/CU but still 8 waves/CU), HALF the
//    LDS traffic per FLOP of the 128x128 core. B-frags read once per
//    K-tile (32 VGPR), A-frags streamed in pairs -> ~230 regs incl acc.
//    Same r12 panel layout + XOR involution (panel stride 16KB; row+128
//    keeps all per-lane XOR constants). Bit-exact K order.
//  - cvt_w3 merged into cvt_data (one flat-grid launch).
//  - ln_rows upgraded to 16B US8 loads.
//  s_f8/pv_f8/softmax unchanged from round-15 passing code.

typedef float f32x4 __attribute__((ext_vector_type(4)));
typedef int i32x4v __attribute__((ext_vector_type(4)));
typedef int i32x8v __attribute__((ext_vector_type(8)));

struct alignas(16) US8 { unsigned short s[8]; };
struct alignas(8)  US4 { unsigned short s[4]; };

// ---------------- workspace layout (bytes, disjoint) ----------------
#define WS_XB   0ull                        // data bf16 [16384][1024] 33.55MB
#define WS_XF8  33554432ull                 // data fp8  [16384][1024] 16.78MB
#define WS_WF8  50331648ull                 // wq,wk,wv fp8 [3][1024][1024] 3.15MB
#define WS_QF8  53477376ull                 // Q fp8 [16384][1024] 16.78MB
#define WS_KF8  70254592ull                 // K fp8 [16384][1024] 16.78MB
#define WS_VT8  87031808ull                 // V^T fp8 [32][1024][512] 16.78MB
#define WS_S    103809024ull                // S bf16 [16384][512] 16.78MB
#define WS_P8   120586240ull                // P fp8 (x256) [16384][512] 8.39MB
#define WS_O    128974848ull                // O bf16 [16384][1024] 33.55MB
#define WS_NEED 162529280ull

__device__ __forceinline__ unsigned short f32_to_bf16(float f) {
  unsigned int u = __builtin_bit_cast(unsigned int, f);
  u += 0x7fffu + ((u >> 16) & 1u);            // round-to-nearest-even
  return (unsigned short)(u >> 16);
}
__device__ __forceinline__ float bf16_to_f32(unsigned short h) {
  return __builtin_bit_cast(float, (unsigned int)h << 16);
}

__device__ __forceinline__ void gload_lds16(const void* g, void* lds) {
  __builtin_amdgcn_global_load_lds(
      (const __attribute__((address_space(1))) unsigned int*)g,
      (__attribute__((address_space(3))) unsigned int*)lds, 16, 0, 0);
}

__device__ __forceinline__ float wave_sum(float v) {
#pragma unroll
  for (int off = 32; off > 0; off >>= 1) v += __shfl_xor(v, off);
  return v;
}
__device__ __forceinline__ float wave_max(float v) {
#pragma unroll
  for (int off = 32; off > 0; off >>= 1) v = fmaxf(v, __shfl_xor(v, off));
  return v;
}

__device__ __forceinline__ unsigned int pk_fp8x4(float a, float b, float c, float d) {
  unsigned int v = 0;
  v = __builtin_amdgcn_cvt_pk_fp8_f32(a, b, v, false);  // bytes 0,1
  v = __builtin_amdgcn_cvt_pk_fp8_f32(c, d, v, true);   // bytes 2,3
  return v;
}
__device__ __forceinline__ unsigned char f32_to_fp8(float v) {
  return (unsigned char)(__builtin_amdgcn_cvt_pk_fp8_f32(v, v, 0, false) & 0xffu);
}

// ------- merged cast: data f32->bf16+fp8, weights f32->fp8, one launch -----
__global__ __launch_bounds__(256) void cvt_all(const float* __restrict__ data,
                                               const float* __restrict__ wq,
                                               const float* __restrict__ wk,
                                               const float* __restrict__ wv,
                                               unsigned short* __restrict__ Xb,
                                               unsigned int* __restrict__ Xf8,
                                               unsigned int* __restrict__ Wf8) {
  const int bid = blockIdx.x;
  if (bid < 8192) {                 // data: 2097152 groups of 8
    int i = bid * 256 + threadIdx.x;
    const float4* sp = (const float4*)(data + (size_t)i * 8);
    float4 a = sp[0], b = sp[1];
    US8 u;
    u.s[0] = f32_to_bf16(a.x); u.s[1] = f32_to_bf16(a.y);
    u.s[2] = f32_to_bf16(a.z); u.s[3] = f32_to_bf16(a.w);
    u.s[4] = f32_to_bf16(b.x); u.s[5] = f32_to_bf16(b.y);
    u.s[6] = f32_to_bf16(b.z); u.s[7] = f32_to_bf16(b.w);
    *(US8*)(Xb + (size_t)i * 8) = u;
    uint2 w;
    w.x = pk_fp8x4(a.x, a.y, a.z, a.w);
    w.y = pk_fp8x4(b.x, b.y, b.z, b.w);
    *(uint2*)(Xf8 + (size_t)i * 2) = w;
  } else {                          // weights: 3 x 512 blocks
    const int r = bid - 8192;
    const int z = r >> 9;
    const float* src = (z == 0) ? wq : (z == 1) ? wk : wv;
    int i = (r & 511) * 256 + threadIdx.x;
    const float4* sp = (const float4*)(src + (size_t)i * 8);
    float4 a = sp[0], b = sp[1];
    uint2 w;
    w.x = pk_fp8x4(a.x, a.y, a.z, a.w);
    w.y = pk_fp8x4(b.x, b.y, b.z, b.w);
    *(uint2*)(Wf8 + (size_t)z * 262144 + (size_t)i * 2) = w;
  }
}

// ============ QKV: 256x256 tile fp8 K=128, 2-slot 64KB, N=3072 ============
// Grid 768 (64 M-tiles x 12 N-tiles), 512 threads = 8 waves (wm=w>>2 row
// half of 128, wn=w&3 col quarter of 64). Per-wave C 128x64 = acc[8][4].
// LDS slot 64KB: A p0[0,16K) p1[16K,32K) (256 rows x 64B each),
//                B p0[32K,48K) p1[48K,64K).
// Swizzle chunk^((row>>1)&3); staging per-lane XOR constant unchanged.
__global__ __launch_bounds__(512, 2) void qkv_256(
    const unsigned char* __restrict__ Xf8, const unsigned char* __restrict__ Wf8,
    unsigned char* __restrict__ Qf8, unsigned char* __restrict__ Kf8,
    unsigned char* __restrict__ Vt8) {
  __shared__ alignas(16) char smc[2][65536];

  const int tid = threadIdx.x;
  const int w = tid >> 6, lane = tid & 63;
  const int wm = w >> 2, wn = w & 3;
  const int lr = lane & 15, lk4 = lane >> 4;

  // bijective XCD-chunked swizzle: 768 blocks, 96 per XCD
  const int bid = blockIdx.x;
  const int wg = (bid & 7) * 96 + (bid >> 3);
  const int bm = wg / 12, bn = wg % 12;

  const char* Ag = (const char*)Xf8 + (size_t)bm * 256 * 1024;
  const char* Bg = (const char*)Wf8 + (size_t)bn * 256 * 1024;

  // staging: dest row = tid>>2 (0..127) within each 8KB region; chunk=tid&3;
  // src chunk = (tid&3) ^ ((tid>>3)&3). Regions: rows+0 / rows+128, k / k+64.
  const int sc = ((tid & 3) ^ ((tid >> 3) & 3)) * 16;
  const char* pA = Ag + (size_t)(tid >> 2) * 1024 + sc;
  const char* pB = Bg + (size_t)(tid >> 2) * 1024 + sc;

  // read: panel = lk4>>1 (stride 16KB), chunks c0=(lk4&1)*2, c0+1,
  // swizzled by (lr>>1)&3; rows: A wm*128+lr (+m*16), B wn*64+lr (+n*16).
  const int swz = (lr >> 1) & 3;
  const int c0 = (lk4 & 1) * 2;
  const int cb0 = ((c0) ^ swz) * 16;
  const int cb1 = ((c0 + 1) ^ swz) * 16;
  const int panA = (lk4 >> 1) * 16384;
  const int panB = 32768 + (lk4 >> 1) * 16384;
  const int rowA = (wm * 128 + lr) * 64;
  const int rowB = (wn * 64 + lr) * 64;

  f32x4 acc[8][4] = {};

#define STAGE8(DD)                                                            \
  do {                                                                        \
    char* dd_ = (DD);                                                         \
    gload_lds16(pA,                dd_ + tid * 16);                           \
    gload_lds16(pA + 131072,       dd_ + 8192 + tid * 16);                    \
    gload_lds16(pA + 64,           dd_ + 16384 + tid * 16);                   \
    gload_lds16(pA + 131072 + 64,  dd_ + 24576 + tid * 16);                   \
    gload_lds16(pB,                dd_ + 32768 + tid * 16);                   \
    gload_lds16(pB + 131072,       dd_ + 40960 + tid * 16);                   \
    gload_lds16(pB + 64,           dd_ + 49152 + tid * 16);                   \
    gload_lds16(pB + 131072 + 64,  dd_ + 57344 + tid * 16);                   \
    pA += 128; pB += 128;                                                     \
  } while (0)

#define MK8(D, OFF)                                                           \
  do {                                                                        \
    i32x4v lo_ = *(const i32x4v*)(sp + (OFF) + cb0);                          \
    i32x4v hi_ = *(const i32x4v*)(sp + (OFF) + cb1);                          \
    D[0] = lo_[0]; D[1] = lo_[1]; D[2] = lo_[2]; D[3] = lo_[3];               \
    D[4] = hi_[0]; D[5] = hi_[1]; D[6] = hi_[2]; D[7] = hi_[3];               \
  } while (0)

#define MFMA128(ACC, AV, BV)                                                  \
  asm("v_mfma_f32_16x16x128_f8f6f4 %0, %1, %2, %0"                            \
      : "+a"(ACC) : "v"(AV), "v"(BV))

  STAGE8(smc[0]);   // prologue: K-tile 0 -> slot 0

#pragma unroll
  for (int t = 0; t < 8; ++t) {
    const int slot = t & 1;
    if (t + 1 < 8) {
      STAGE8(smc[slot ^ 1]);
      asm volatile("s_waitcnt vmcnt(8)" ::: "memory");
    } else {
      asm volatile("s_waitcnt vmcnt(0)" ::: "memory");
    }
    __builtin_amdgcn_s_barrier();
    __builtin_amdgcn_sched_barrier(0);
    const char* sp = smc[slot];
    i32x8v b0, b1, b2, b3;
    MK8(b0, panB + rowB);          MK8(b1, panB + rowB + 1024);
    MK8(b2, panB + rowB + 2048);   MK8(b3, panB + rowB + 3072);
#pragma unroll
    for (int mb = 0; mb < 8; mb += 2) {
      i32x8v a0, a1;
      MK8(a0, panA + rowA + mb * 1024);
      MK8(a1, panA + rowA + (mb + 1) * 1024);
      __builtin_amdgcn_s_setprio(1);
      MFMA128(acc[mb][0], a0, b0);     MFMA128(acc[mb][1], a0, b1);
      MFMA128(acc[mb][2], a0, b2);     MFMA128(acc[mb][3], a0, b3);
      MFMA128(acc[mb + 1][0], a1, b0); MFMA128(acc[mb + 1][1], a1, b1);
      MFMA128(acc[mb + 1][2], a1, b2); MFMA128(acc[mb + 1][3], a1, b3);
      __builtin_amdgcn_s_setprio(0);
    }
    __builtin_amdgcn_sched_barrier(0);
    __builtin_amdgcn_s_barrier();
  }

#undef MFMA128
#undef MK8
#undef STAGE8

  // epilogue: C row = bm*256 + wm*128 + m*16 + (lane>>4)*4 + i,
  //           col within matrix z=bn>>2: (bn&3)*256 + wn*64 + n*16 + lr
  const int cr = lk4 << 2;
  const int z = bn >> 2;
  const int gr0 = bm * 256 + wm * 128;
  const int gc0 = (bn & 3) * 256 + wn * 64;
  if (z < 2) {
    unsigned char* C = (z == 0) ? Qf8 : Kf8;
#pragma unroll
    for (int m = 0; m < 8; ++m)
#pragma unroll
      for (int n = 0; n < 4; ++n)
#pragma unroll
        for (int i = 0; i < 4; ++i)
          C[(size_t)(gr0 + m * 16 + cr + i) * 1024 + (gc0 + n * 16 + lr)] =
              f32_to_fp8(acc[m][n][i]);
  } else {
    // Vt8[b][d][t] = V[b*512+t][d]; 4 consecutive t -> one uint store
#pragma unroll
    for (int m = 0; m < 8; ++m) {
      const int gr = gr0 + m * 16 + cr;
      const int b = gr >> 9, tt = gr & 511;
#pragma unroll
      for (int n = 0; n < 4; ++n) {
        const int d = gc0 + n * 16 + lr;
        unsigned int u = pk_fp8x4(acc[m][n][0], acc[m][n][1],
                                  acc[m][n][2], acc[m][n][3]);
        *(unsigned int*)(Vt8 + ((size_t)b * 1024 + d) * 512 + tt) = u;
      }
    }
  }
}

// ============ fp8 K=128 GEMM core, 128x128 tile, 256 threads (r15) ========
template <int KB, int NKT>
__device__ __forceinline__ void f8c128(const char* __restrict__ Ag,
                                       const char* __restrict__ Bg,
                                       char* lds, f32x4 (&acc)[4][4]) {
  const int tid = threadIdx.x;
  const int w = tid >> 6, lane = tid & 63;
  const int wm = w >> 1, wn = w & 1;
  const int lr = lane & 15, lk4 = lane >> 4;

  const int sc = ((tid & 3) ^ ((tid >> 3) & 3)) * 16;
  const char* pA = Ag + (size_t)(tid >> 2) * KB + sc;
  const char* pB = Bg + (size_t)(tid >> 2) * KB + sc;
  const size_t R64 = (size_t)64 * KB;

  const int swz = (lr >> 1) & 3;
  const int c0 = (lk4 & 1) * 2;
  const int cb0 = ((c0) ^ swz) * 16;
  const int cb1 = ((c0 + 1) ^ swz) * 16;
  const int panA = (lk4 >> 1) * 8192;
  const int panB = 16384 + (lk4 >> 1) * 8192;
  const int rowA = (wm * 64 + lr) * 64;
  const int rowB = (wn * 64 + lr) * 64;

#define STAGE8(DD)                                                            \
  do {                                                                        \
    char* dd_ = (DD);                                                         \
    gload_lds16(pA,            dd_ + tid * 16);                               \
    gload_lds16(pA + R64,      dd_ + 4096 + tid * 16);                        \
    gload_lds16(pA + 64,       dd_ + 8192 + tid * 16);                        \
    gload_lds16(pA + R64 + 64, dd_ + 12288 + tid * 16);                       \
    gload_lds16(pB,            dd_ + 16384 + tid * 16);                       \
    gload_lds16(pB + R64,      dd_ + 20480 + tid * 16);                       \
    gload_lds16(pB + 64,       dd_ + 24576 + tid * 16);                       \
    gload_lds16(pB + R64 + 64, dd_ + 28672 + tid * 16);                       \
    pA += 128; pB += 128;                                                     \
  } while (0)

#define MK8(D, OFF)                                                           \
  do {                                                                        \
    i32x4v lo_ = *(const i32x4v*)(sp + (OFF) + cb0);                          \
    i32x4v hi_ = *(const i32x4v*)(sp + (OFF) + cb1);                          \
    D[0] = lo_[0]; D[1] = lo_[1]; D[2] = lo_[2]; D[3] = lo_[3];               \
    D[4] = hi_[0]; D[5] = hi_[1]; D[6] = hi_[2]; D[7] = hi_[3];               \
  } while (0)

#define MFMA128(ACC, AV, BV)                                                  \
  asm("v_mfma_f32_16x16x128_f8f6f4 %0, %1, %2, %0"                            \
      : "+a"(ACC) : "v"(AV), "v"(BV))

  STAGE8(lds);   // prologue: K-tile 0 -> slot 0

#pragma unroll
  for (int t = 0; t < NKT; ++t) {
    const int slot = t & 1;
    if (t + 1 < NKT) {
      STAGE8(lds + (slot ^ 1) * 32768);
      asm volatile("s_waitcnt vmcnt(8)" ::: "memory");
    } else {
      asm volatile("s_waitcnt vmcnt(0)" ::: "memory");
    }
    __builtin_amdgcn_s_barrier();
    __builtin_amdgcn_sched_barrier(0);
    const char* sp = lds + slot * 32768;
    i32x8v a0, a1, b0, b1, b2, b3;
    MK8(a0, panA + rowA);          MK8(a1, panA + rowA + 1024);
    MK8(b0, panB + rowB);          MK8(b1, panB + rowB + 1024);
    MK8(b2, panB + rowB + 2048);   MK8(b3, panB + rowB + 3072);
    __builtin_amdgcn_s_setprio(1);
    MFMA128(acc[0][0], a0, b0); MFMA128(acc[0][1], a0, b1);
    MFMA128(acc[0][2], a0, b2); MFMA128(acc[0][3], a0, b3);
    MFMA128(acc[1][0], a1, b0); MFMA128(acc[1][1], a1, b1);
    MFMA128(acc[1][2], a1, b2); MFMA128(acc[1][3], a1, b3);
    __builtin_amdgcn_s_setprio(0);
    i32x8v a2, a3;
    MK8(a2, panA + rowA + 2048);   MK8(a3, panA + rowA + 3072);
    __builtin_amdgcn_s_setprio(1);
    MFMA128(acc[2][0], a2, b0); MFMA128(acc[2][1], a2, b1);
    MFMA128(acc[2][2], a2, b2); MFMA128(acc[2][3], a2, b3);
    MFMA128(acc[3][0], a3, b0); MFMA128(acc[3][1], a3, b1);
    MFMA128(acc[3][2], a3, b2); MFMA128(acc[3][3], a3, b3);
    __builtin_amdgcn_s_setprio(0);
    __builtin_amdgcn_sched_barrier(0);
    __builtin_amdgcn_s_barrier();
  }

#undef MFMA128
#undef MK8
#undef STAGE8
}

// ============ S = Q K^T per batch (fp8 in, bf16 out) ============
__global__ __launch_bounds__(256, 2) void s_f8(
    const unsigned char* __restrict__ Qf8, const unsigned char* __restrict__ Kf8,
    unsigned short* __restrict__ S) {
  __shared__ alignas(16) char smc[2][32768];
  const int bn = blockIdx.x, bm = blockIdx.y, b = blockIdx.z;
  const char* Ag = (const char*)Qf8 + ((size_t)b * 512 + bm * 128) * 1024;
  const char* Bg = (const char*)Kf8 + ((size_t)b * 512 + bn * 128) * 1024;
  f32x4 acc[4][4] = {};
  f8c128<1024, 8>(Ag, Bg, &smc[0][0], acc);

  const int tid = threadIdx.x;
  const int w = tid >> 6, lane = tid & 63;
  const int wm = w >> 1, wn = w & 1;
  const int lr = lane & 15, lk4 = lane >> 4;
  const int cr = lk4 << 2;
  unsigned short* Cp = S + (size_t)b * 262144;
  const int rbase = bm * 128 + wm * 64;
  const int cbase = bn * 128 + wn * 64;
#pragma unroll
  for (int m = 0; m < 4; ++m)
#pragma unroll
    for (int n = 0; n < 4; ++n)
#pragma unroll
      for (int i = 0; i < 4; ++i)
        Cp[(size_t)(rbase + m * 16 + cr + i) * 512 + (cbase + n * 16 + lr)] =
            f32_to_bf16(acc[m][n][i]);
}

// -------- row L2-normalize + softmax; attn f32 out + P fp8 (x256) --------
__global__ __launch_bounds__(256) void softmax_rows(const unsigned short* __restrict__ S,
                                                    float* __restrict__ out,
                                                    unsigned char* __restrict__ P8) {
  const int w = threadIdx.x >> 6, lane = threadIdx.x & 63;
  const int r = blockIdx.x * 4 + w;          // global row 0..16383
  const int b = r >> 9, s = r & 511;
  US8 v = *(const US8*)(S + (size_t)r * 512 + lane * 8);
  float x[8];
#pragma unroll
  for (int i = 0; i < 8; ++i) x[i] = bf16_to_f32(v.s[i]);
  float ss = 0.f;
#pragma unroll
  for (int i = 0; i < 8; ++i) ss += x[i] * x[i];
  ss = wave_sum(ss);
  const float inv = 1.0f / fmaxf(sqrtf(ss), 1e-12f);
  float mx = -1e30f;
#pragma unroll
  for (int i = 0; i < 8; ++i) { x[i] *= inv; mx = fmaxf(mx, x[i]); }
  mx = wave_max(mx);
  float se = 0.f;
#pragma unroll
  for (int i = 0; i < 8; ++i) { x[i] = __expf(x[i] - mx); se += x[i]; }
  se = wave_sum(se);
  const float rs = 1.0f / se;
#pragma unroll
  for (int i = 0; i < 8; ++i) x[i] *= rs;

  float* op = out + (size_t)b * 786432 + 524288 + (size_t)s * 512 + lane * 8;
  float4 o0 = {x[0], x[1], x[2], x[3]};
  float4 o1 = {x[4], x[5], x[6], x[7]};
  *(float4*)op = o0;
  *(float4*)(op + 4) = o1;
  // P stored x256 (attn ~2e-3 is on e4m3's subnormal floor; x256 -> normal)
  uint2 pw;
  pw.x = pk_fp8x4(x[0] * 256.f, x[1] * 256.f, x[2] * 256.f, x[3] * 256.f);
  pw.y = pk_fp8x4(x[4] * 256.f, x[5] * 256.f, x[6] * 256.f, x[7] * 256.f);
  *(uint2*)(P8 + (size_t)r * 512 + lane * 8) = pw;
}

// ============ O = P V via Vt (fp8 in, bf16 out, 1/256 unscale) ============
__global__ __launch_bounds__(256, 2) void pv_f8(
    const unsigned char* __restrict__ P8, const unsigned char* __restrict__ Vt8,
    unsigned short* __restrict__ O) {
  __shared__ alignas(16) char smc[2][32768];
  const int bn = blockIdx.x, bm = blockIdx.y, b = blockIdx.z;
  const char* Ag = (const char*)P8 + ((size_t)b * 512 + bm * 128) * 512;
  const char* Bg = (const char*)Vt8 + ((size_t)b * 1024 + bn * 128) * 512;
  f32x4 acc[4][4] = {};
  f8c128<512, 4>(Ag, Bg, &smc[0][0], acc);

  const int tid = threadIdx.x;
  const int w = tid >> 6, lane = tid & 63;
  const int wm = w >> 1, wn = w & 1;
  const int lr = lane & 15, lk4 = lane >> 4;
  const int cr = lk4 << 2;
  const int grow = b * 512 + bm * 128 + wm * 64;
  const int cbase = bn * 128 + wn * 64;
#pragma unroll
  for (int m = 0; m < 4; ++m)
#pragma unroll
    for (int n = 0; n < 4; ++n)
#pragma unroll
      for (int i = 0; i < 4; ++i)
        O[(size_t)(grow + m * 16 + cr + i) * 1024 + (cbase + n * 16 + lr)] =
            f32_to_bf16(acc[m][n][i] * 0.00390625f);
}

// ---------------- residual + LayerNorm, wave per row (16B loads) ---------
__global__ __launch_bounds__(256) void ln_rows(const unsigned short* __restrict__ O,
                                               const unsigned short* __restrict__ Xb,
                                               const float* __restrict__ gamma,
                                               const float* __restrict__ beta,
                                               float* __restrict__ out) {
  const int w = threadIdx.x >> 6, lane = threadIdx.x & 63;
  const int r = blockIdx.x * 4 + w;
  const int b = r >> 9, s = r & 511;
  const unsigned short* orow = O + (size_t)r * 1024;
  const unsigned short* drow = Xb + (size_t)r * 1024;
  float x[16];
  float sm = 0.f, sq = 0.f;
#pragma unroll
  for (int j = 0; j < 2; ++j) {
    const int col = j * 512 + lane * 8;
    US8 o8 = *(const US8*)(orow + col);
    US8 d8 = *(const US8*)(drow + col);
#pragma unroll
    for (int k = 0; k < 8; ++k)
      x[j * 8 + k] = bf16_to_f32(o8.s[k]) + bf16_to_f32(d8.s[k]);
  }
#pragma unroll
  for (int i = 0; i < 16; ++i) { sm += x[i]; sq += x[i] * x[i]; }
  sm = wave_sum(sm);
  sq = wave_sum(sq);
  const float mean = sm * (1.0f / 1024.0f);
  const float var = sq * (1.0f / 1024.0f) - mean * mean;
  const float rstd = rsqrtf(var + 1e-6f);
  float* op = out + (size_t)b * 786432 + (size_t)s * 1024;
#pragma unroll
  for (int j = 0; j < 2; ++j) {
    const int col = j * 512 + lane * 8;
    float4 g0 = *(const float4*)(gamma + col);
    float4 g1 = *(const float4*)(gamma + col + 4);
    float4 b0 = *(const float4*)(beta + col);
    float4 b1 = *(const float4*)(beta + col + 4);
    float4 y0, y1;
    y0.x = (x[j * 8 + 0] - mean) * rstd * g0.x + b0.x;
    y0.y = (x[j * 8 + 1] - mean) * rstd * g0.y + b0.y;
    y0.z = (x[j * 8 + 2] - mean) * rstd * g0.z + b0.z;
    y0.w = (x[j * 8 + 3] - mean) * rstd * g0.w + b0.w;
    y1.x = (x[j * 8 + 4] - mean) * rstd * g1.x + b1.x;
    y1.y = (x[j * 8 + 5] - mean) * rstd * g1.y + b1.y;
    y1.z = (x[j * 8 + 6] - mean) * rstd * g1.z + b1.z;
    y1.w = (x[j * 8 + 7] - mean) * rstd * g1.w + b1.w;
    *(float4*)(op + col) = y0;
    *(float4*)(op + col + 4) = y1;
  }
}

extern "C" void kernel_launch(void* const* d_in, const int* in_sizes, int n_in,
                              void* d_out, int out_size, void* d_ws, size_t ws_size,
                              hipStream_t stream) {
  const float* data  = (const float*)d_in[0];
  const float* wq    = (const float*)d_in[1];
  const float* wk    = (const float*)d_in[2];
  const float* wv    = (const float*)d_in[3];
  const float* gamma = (const float*)d_in[4];
  const float* beta  = (const float*)d_in[5];
  float* out = (float*)d_out;
  char* ws = (char*)d_ws;
  if (ws_size < WS_NEED) return;

  unsigned short* Xb  = (unsigned short*)(ws + WS_XB);
  unsigned int*   Xf8 = (unsigned int*)(ws + WS_XF8);
  unsigned int*   Wf8 = (unsigned int*)(ws + WS_WF8);
  unsigned char*  Qf8 = (unsigned char*)(ws + WS_QF8);
  unsigned char*  Kf8 = (unsigned char*)(ws + WS_KF8);
  unsigned char*  Vt8 = (unsigned char*)(ws + WS_VT8);
  unsigned short* S   = (unsigned short*)(ws + WS_S);
  unsigned char*  P8  = (unsigned char*)(ws + WS_P8);
  unsigned short* O   = (unsigned short*)(ws + WS_O);

  cvt_all<<<9728, 256, 0, stream>>>(data, wq, wk, wv, Xb, Xf8, Wf8);
  qkv_256<<<768, 512, 0, stream>>>((const unsigned char*)Xf8,
                                   (const unsigned char*)Wf8, Qf8, Kf8, Vt8);
  s_f8<<<dim3(4, 4, 32), 256, 0, stream>>>(Qf8, Kf8, S);
  softmax_rows<<<4096, 256, 0, stream>>>(S, out, P8);
  pv_f8<<<dim3(8, 4, 32), 256, 0, stream>>>(P8, Vt8, O);
  ln_rows<<<4096, 256, 0, stream>>>(O, Xb, gamma, beta, out);
}

// Round 17
// 165.480 us; speedup vs baseline: 1.0313x; 1.0313x over previous
//
#include <hip/hip_runtime.h>
#include <hip/hip_bf16.h>

// ModalAttention fused pipeline, MI355X (gfx950).
//
// Math: attn/|global_min| followed by L2-normalize cancels any positive
// per-tensor scale (incl. /sqrt(h)) -> softmax input = s_row/||s_row||_2,
// s = q.k. No global-min reduction needed.
//
// Round 17: qkv reverted to the r15-proven 128x128 fp8 core (2 blocks/CU
// TLP beats the 256-tile's reuse; r16 A/B confirmed). Intermediate
// dtypes shrunk: S fp8 (|S|<~180 fits e4m3; attn err ~3e-5) and O fp8
// scaled x16 (O ~ [0.002,0.3] -> normal range; out err +~0.01). fp8
// decode is branchless bit-math: f32 = bitcast(sign<<31 | (b&0x7F)<<20)
// * 2^120 (exact for e4m3 incl. subnormals). P fp8 x256 as before.

typedef float f32x4 __attribute__((ext_vector_type(4)));
typedef int i32x4v __attribute__((ext_vector_type(4)));
typedef int i32x8v __attribute__((ext_vector_type(8)));

struct alignas(16) US8 { unsigned short s[8]; };
struct alignas(8)  US4 { unsigned short s[4]; };

// ---------------- workspace layout (bytes, disjoint) ----------------
#define WS_XB   0ull                        // data bf16 [16384][1024] 33.55MB
#define WS_XF8  33554432ull                 // data fp8  [16384][1024] 16.78MB
#define WS_WF8  50331648ull                 // wq,wk,wv fp8 [3][1024][1024] 3.15MB
#define WS_QF8  53477376ull                 // Q fp8 [16384][1024] 16.78MB
#define WS_KF8  70254592ull                 // K fp8 [16384][1024] 16.78MB
#define WS_VT8  87031808ull                 // V^T fp8 [32][1024][512] 16.78MB
#define WS_S8   103809024ull                // S fp8 [16384][512] 8.39MB
#define WS_P8   112197632ull                // P fp8 (x256) [16384][512] 8.39MB
#define WS_O8   120586240ull                // O fp8 (x16) [16384][1024] 16.78MB
#define WS_NEED 137363456ull

__device__ __forceinline__ unsigned short f32_to_bf16(float f) {
  unsigned int u = __builtin_bit_cast(unsigned int, f);
  u += 0x7fffu + ((u >> 16) & 1u);            // round-to-nearest-even
  return (unsigned short)(u >> 16);
}
__device__ __forceinline__ float bf16_to_f32(unsigned short h) {
  return __builtin_bit_cast(float, (unsigned int)h << 16);
}

__device__ __forceinline__ void gload_lds16(const void* g, void* lds) {
  __builtin_amdgcn_global_load_lds(
      (const __attribute__((address_space(1))) unsigned int*)g,
      (__attribute__((address_space(3))) unsigned int*)lds, 16, 0, 0);
}

__device__ __forceinline__ float wave_sum(float v) {
#pragma unroll
  for (int off = 32; off > 0; off >>= 1) v += __shfl_xor(v, off);
  return v;
}
__device__ __forceinline__ float wave_max(float v) {
#pragma unroll
  for (int off = 32; off > 0; off >>= 1) v = fmaxf(v, __shfl_xor(v, off));
  return v;
}

__device__ __forceinline__ unsigned int pk_fp8x4(float a, float b, float c, float d) {
  unsigned int v = 0;
  v = __builtin_amdgcn_cvt_pk_fp8_f32(a, b, v, false);  // bytes 0,1
  v = __builtin_amdgcn_cvt_pk_fp8_f32(c, d, v, true);   // bytes 2,3
  return v;
}
__device__ __forceinline__ unsigned char f32_to_fp8(float v) {
  return (unsigned char)(__builtin_amdgcn_cvt_pk_fp8_f32(v, v, 0, false) & 0xffu);
}
// exact e4m3 -> f32 (normals AND subnormals): value bits placed at the
// bottom of the f32 exponent field, then rescaled by 2^120.
__device__ __forceinline__ float fp8_to_f32(unsigned int b) {
  unsigned int u = ((b & 0x80u) << 24) | ((b & 0x7Fu) << 20);
  return __builtin_bit_cast(float, u) * 0x1p120f;
}

// ------- merged cast: data f32->bf16+fp8, weights f32->fp8, one launch -----
__global__ __launch_bounds__(256) void cvt_all(const float* __restrict__ data,
                                               const float* __restrict__ wq,
                                               const float* __restrict__ wk,
                                               const float* __restrict__ wv,
                                               unsigned short* __restrict__ Xb,
                                               unsigned int* __restrict__ Xf8,
                                               unsigned int* __restrict__ Wf8) {
  const int bid = blockIdx.x;
  if (bid < 8192) {                 // data: 2097152 groups of 8
    int i = bid * 256 + threadIdx.x;
    const float4* sp = (const float4*)(data + (size_t)i * 8);
    float4 a = sp[0], b = sp[1];
    US8 u;
    u.s[0] = f32_to_bf16(a.x); u.s[1] = f32_to_bf16(a.y);
    u.s[2] = f32_to_bf16(a.z); u.s[3] = f32_to_bf16(a.w);
    u.s[4] = f32_to_bf16(b.x); u.s[5] = f32_to_bf16(b.y);
    u.s[6] = f32_to_bf16(b.z); u.s[7] = f32_to_bf16(b.w);
    *(US8*)(Xb + (size_t)i * 8) = u;
    uint2 w;
    w.x = pk_fp8x4(a.x, a.y, a.z, a.w);
    w.y = pk_fp8x4(b.x, b.y, b.z, b.w);
    *(uint2*)(Xf8 + (size_t)i * 2) = w;
  } else {                          // weights: 3 x 512 blocks
    const int r = bid - 8192;
    const int z = r >> 9;
    const float* src = (z == 0) ? wq : (z == 1) ? wk : wv;
    int i = (r & 511) * 256 + threadIdx.x;
    const float4* sp = (const float4*)(src + (size_t)i * 8);
    float4 a = sp[0], b = sp[1];
    uint2 w;
    w.x = pk_fp8x4(a.x, a.y, a.z, a.w);
    w.y = pk_fp8x4(b.x, b.y, b.z, b.w);
    *(uint2*)(Wf8 + (size_t)z * 262144 + (size_t)i * 2) = w;
  }
}

// ============ fp8 K=128 GEMM core, 128x128 tile, 256 threads (r15) ========
template <int KB, int NKT>
__device__ __forceinline__ void f8c128(const char* __restrict__ Ag,
                                       const char* __restrict__ Bg,
                                       char* lds, f32x4 (&acc)[4][4]) {
  const int tid = threadIdx.x;
  const int w = tid >> 6, lane = tid & 63;
  const int wm = w >> 1, wn = w & 1;
  const int lr = lane & 15, lk4 = lane >> 4;

  const int sc = ((tid & 3) ^ ((tid >> 3) & 3)) * 16;
  const char* pA = Ag + (size_t)(tid >> 2) * KB + sc;
  const char* pB = Bg + (size_t)(tid >> 2) * KB + sc;
  const size_t R64 = (size_t)64 * KB;

  const int swz = (lr >> 1) & 3;
  const int c0 = (lk4 & 1) * 2;
  const int cb0 = ((c0) ^ swz) * 16;
  const int cb1 = ((c0 + 1) ^ swz) * 16;
  const int panA = (lk4 >> 1) * 8192;
  const int panB = 16384 + (lk4 >> 1) * 8192;
  const int rowA = (wm * 64 + lr) * 64;
  const int rowB = (wn * 64 + lr) * 64;

#define STAGE8(DD)                                                            \
  do {                                                                        \
    char* dd_ = (DD);                                                         \
    gload_lds16(pA,            dd_ + tid * 16);                               \
    gload_lds16(pA + R64,      dd_ + 4096 + tid * 16);                        \
    gload_lds16(pA + 64,       dd_ + 8192 + tid * 16);                        \
    gload_lds16(pA + R64 + 64, dd_ + 12288 + tid * 16);                       \
    gload_lds16(pB,            dd_ + 16384 + tid * 16);                       \
    gload_lds16(pB + R64,      dd_ + 20480 + tid * 16);                       \
    gload_lds16(pB + 64,       dd_ + 24576 + tid * 16);                       \
    gload_lds16(pB + R64 + 64, dd_ + 28672 + tid * 16);                       \
    pA += 128; pB += 128;                                                     \
  } while (0)

#define MK8(D, OFF)                                                           \
  do {                                                                        \
    i32x4v lo_ = *(const i32x4v*)(sp + (OFF) + cb0);                          \
    i32x4v hi_ = *(const i32x4v*)(sp + (OFF) + cb1);                          \
    D[0] = lo_[0]; D[1] = lo_[1]; D[2] = lo_[2]; D[3] = lo_[3];               \
    D[4] = hi_[0]; D[5] = hi_[1]; D[6] = hi_[2]; D[7] = hi_[3];               \
  } while (0)

#define MFMA128(ACC, AV, BV)                                                  \
  asm("v_mfma_f32_16x16x128_f8f6f4 %0, %1, %2, %0"                            \
      : "+a"(ACC) : "v"(AV), "v"(BV))

  STAGE8(lds);   // prologue: K-tile 0 -> slot 0

#pragma unroll
  for (int t = 0; t < NKT; ++t) {
    const int slot = t & 1;
    if (t + 1 < NKT) {
      STAGE8(lds + (slot ^ 1) * 32768);
      asm volatile("s_waitcnt vmcnt(8)" ::: "memory");
    } else {
      asm volatile("s_waitcnt vmcnt(0)" ::: "memory");
    }
    __builtin_amdgcn_s_barrier();
    __builtin_amdgcn_sched_barrier(0);
    const char* sp = lds + slot * 32768;
    i32x8v a0, a1, b0, b1, b2, b3;
    MK8(a0, panA + rowA);          MK8(a1, panA + rowA + 1024);
    MK8(b0, panB + rowB);          MK8(b1, panB + rowB + 1024);
    MK8(b2, panB + rowB + 2048);   MK8(b3, panB + rowB + 3072);
    __builtin_amdgcn_s_setprio(1);
    MFMA128(acc[0][0], a0, b0); MFMA128(acc[0][1], a0, b1);
    MFMA128(acc[0][2], a0, b2); MFMA128(acc[0][3], a0, b3);
    MFMA128(acc[1][0], a1, b0); MFMA128(acc[1][1], a1, b1);
    MFMA128(acc[1][2], a1, b2); MFMA128(acc[1][3], a1, b3);
    __builtin_amdgcn_s_setprio(0);
    i32x8v a2, a3;
    MK8(a2, panA + rowA + 2048);   MK8(a3, panA + rowA + 3072);
    __builtin_amdgcn_s_setprio(1);
    MFMA128(acc[2][0], a2, b0); MFMA128(acc[2][1], a2, b1);
    MFMA128(acc[2][2], a2, b2); MFMA128(acc[2][3], a2, b3);
    MFMA128(acc[3][0], a3, b0); MFMA128(acc[3][1], a3, b1);
    MFMA128(acc[3][2], a3, b2); MFMA128(acc[3][3], a3, b3);
    __builtin_amdgcn_s_setprio(0);
    __builtin_amdgcn_sched_barrier(0);
    __builtin_amdgcn_s_barrier();
  }

#undef MFMA128
#undef MK8
#undef STAGE8
}

// ============ QKV: fp8 in/out (Q,K row-major; Vt transposed), r15 ========
__global__ __launch_bounds__(256, 2) void qkv_128(
    const unsigned char* __restrict__ Xf8, const unsigned char* __restrict__ Wf8,
    unsigned char* __restrict__ Qf8, unsigned char* __restrict__ Kf8,
    unsigned char* __restrict__ Vt8) {
  __shared__ alignas(16) char smc[2][32768];
  const int bid = blockIdx.x;
  const int wg = (bid & 7) * 384 + (bid >> 3);   // bijective, 3072 % 8 == 0
  const int bm = wg / 24, bn = wg % 24;
  const char* Ag = (const char*)Xf8 + (size_t)bm * 128 * 1024;
  const char* Bg = (const char*)Wf8 + (size_t)bn * 128 * 1024;
  f32x4 acc[4][4] = {};
  f8c128<1024, 8>(Ag, Bg, &smc[0][0], acc);

  const int tid = threadIdx.x;
  const int w = tid >> 6, lane = tid & 63;
  const int wm = w >> 1, wn = w & 1;
  const int lr = lane & 15, lk4 = lane >> 4;
  const int cr = lk4 << 2;
  const int z = bn >> 3;                       // 0=Q 1=K 2=V
  const int gr0 = bm * 128 + wm * 64;
  const int gc0 = (bn & 7) * 128 + wn * 64;
  if (z < 2) {
    unsigned char* C = (z == 0) ? Qf8 : Kf8;
#pragma unroll
    for (int m = 0; m < 4; ++m)
#pragma unroll
      for (int n = 0; n < 4; ++n)
#pragma unroll
        for (int i = 0; i < 4; ++i)
          C[(size_t)(gr0 + m * 16 + cr + i) * 1024 + (gc0 + n * 16 + lr)] =
              f32_to_fp8(acc[m][n][i]);
  } else {
    // Vt8[b][d][t] = V[b*512+t][d]; 4 consecutive t -> one uint store
#pragma unroll
    for (int m = 0; m < 4; ++m) {
      const int gr = gr0 + m * 16 + cr;
      const int b = gr >> 9, tt = gr & 511;
#pragma unroll
      for (int n = 0; n < 4; ++n) {
        const int d = gc0 + n * 16 + lr;
        unsigned int u = pk_fp8x4(acc[m][n][0], acc[m][n][1],
                                  acc[m][n][2], acc[m][n][3]);
        *(unsigned int*)(Vt8 + ((size_t)b * 1024 + d) * 512 + tt) = u;
      }
    }
  }
}

// ============ S = Q K^T per batch (fp8 in, fp8 out) ============
__global__ __launch_bounds__(256, 2) void s_f8(
    const unsigned char* __restrict__ Qf8, const unsigned char* __restrict__ Kf8,
    unsigned char* __restrict__ S8) {
  __shared__ alignas(16) char smc[2][32768];
  const int bn = blockIdx.x, bm = blockIdx.y, b = blockIdx.z;
  const char* Ag = (const char*)Qf8 + ((size_t)b * 512 + bm * 128) * 1024;
  const char* Bg = (const char*)Kf8 + ((size_t)b * 512 + bn * 128) * 1024;
  f32x4 acc[4][4] = {};
  f8c128<1024, 8>(Ag, Bg, &smc[0][0], acc);

  const int tid = threadIdx.x;
  const int w = tid >> 6, lane = tid & 63;
  const int wm = w >> 1, wn = w & 1;
  const int lr = lane & 15, lk4 = lane >> 4;
  const int cr = lk4 << 2;
  unsigned char* Cp = S8 + (size_t)b * 262144;
  const int rbase = bm * 128 + wm * 64;
  const int cbase = bn * 128 + wn * 64;
#pragma unroll
  for (int m = 0; m < 4; ++m)
#pragma unroll
    for (int n = 0; n < 4; ++n)
#pragma unroll
      for (int i = 0; i < 4; ++i)
        Cp[(size_t)(rbase + m * 16 + cr + i) * 512 + (cbase + n * 16 + lr)] =
            f32_to_fp8(acc[m][n][i]);
}

// -------- row L2-normalize + softmax; attn f32 out + P fp8 (x256) --------
__global__ __launch_bounds__(256) void softmax_rows(const unsigned char* __restrict__ S8,
                                                    float* __restrict__ out,
                                                    unsigned char* __restrict__ P8) {
  const int w = threadIdx.x >> 6, lane = threadIdx.x & 63;
  const int r = blockIdx.x * 4 + w;          // global row 0..16383
  const int b = r >> 9, s = r & 511;
  uint2 v = *(const uint2*)(S8 + (size_t)r * 512 + lane * 8);
  float x[8];
#pragma unroll
  for (int i = 0; i < 4; ++i) x[i] = fp8_to_f32((v.x >> (8 * i)) & 0xffu);
#pragma unroll
  for (int i = 0; i < 4; ++i) x[4 + i] = fp8_to_f32((v.y >> (8 * i)) & 0xffu);
  float ss = 0.f;
#pragma unroll
  for (int i = 0; i < 8; ++i) ss += x[i] * x[i];
  ss = wave_sum(ss);
  const float inv = 1.0f / fmaxf(sqrtf(ss), 1e-12f);
  float mx = -1e30f;
#pragma unroll
  for (int i = 0; i < 8; ++i) { x[i] *= inv; mx = fmaxf(mx, x[i]); }
  mx = wave_max(mx);
  float se = 0.f;
#pragma unroll
  for (int i = 0; i < 8; ++i) { x[i] = __expf(x[i] - mx); se += x[i]; }
  se = wave_sum(se);
  const float rs = 1.0f / se;
#pragma unroll
  for (int i = 0; i < 8; ++i) x[i] *= rs;

  float* op = out + (size_t)b * 786432 + 524288 + (size_t)s * 512 + lane * 8;
  float4 o0 = {x[0], x[1], x[2], x[3]};
  float4 o1 = {x[4], x[5], x[6], x[7]};
  *(float4*)op = o0;
  *(float4*)(op + 4) = o1;
  // P stored x256 (attn ~2e-3 is on e4m3's subnormal floor; x256 -> normal)
  uint2 pw;
  pw.x = pk_fp8x4(x[0] * 256.f, x[1] * 256.f, x[2] * 256.f, x[3] * 256.f);
  pw.y = pk_fp8x4(x[4] * 256.f, x[5] * 256.f, x[6] * 256.f, x[7] * 256.f);
  *(uint2*)(P8 + (size_t)r * 512 + lane * 8) = pw;
}

// ====== O = P V via Vt (fp8 in, fp8 out x16: acc*(16/256) = acc/16) ======
__global__ __launch_bounds__(256, 2) void pv_f8(
    const unsigned char* __restrict__ P8, const unsigned char* __restrict__ Vt8,
    unsigned char* __restrict__ O8) {
  __shared__ alignas(16) char smc[2][32768];
  const int bn = blockIdx.x, bm = blockIdx.y, b = blockIdx.z;
  const char* Ag = (const char*)P8 + ((size_t)b * 512 + bm * 128) * 512;
  const char* Bg = (const char*)Vt8 + ((size_t)b * 1024 + bn * 128) * 512;
  f32x4 acc[4][4] = {};
  f8c128<512, 4>(Ag, Bg, &smc[0][0], acc);

  const int tid = threadIdx.x;
  const int w = tid >> 6, lane = tid & 63;
  const int wm = w >> 1, wn = w & 1;
  const int lr = lane & 15, lk4 = lane >> 4;
  const int cr = lk4 << 2;
  const int grow = b * 512 + bm * 128 + wm * 64;
  const int cbase = bn * 128 + wn * 64;
#pragma unroll
  for (int m = 0; m < 4; ++m)
#pragma unroll
    for (int n = 0; n < 4; ++n)
#pragma unroll
      for (int i = 0; i < 4; ++i)
        O8[(size_t)(grow + m * 16 + cr + i) * 1024 + (cbase + n * 16 + lr)] =
            f32_to_fp8(acc[m][n][i] * 0.0625f);   // /256 then x16
}

// ------- residual + LayerNorm; O fp8 (x16) + Xb bf16 -> out f32 -------
__global__ __launch_bounds__(256) void ln_rows(const unsigned char* __restrict__ O8,
                                               const unsigned short* __restrict__ Xb,
                                               const float* __restrict__ gamma,
                                               const float* __restrict__ beta,
                                               float* __restrict__ out) {
  const int w = threadIdx.x >> 6, lane = threadIdx.x & 63;
  const int r = blockIdx.x * 4 + w;
  const int b = r >> 9, s = r & 511;
  const int col0 = lane * 16;                // 16 consecutive cols per lane
  uint4 o16 = *(const uint4*)(O8 + (size_t)r * 1024 + col0);
  US8 d0 = *(const US8*)(Xb + (size_t)r * 1024 + col0);
  US8 d1 = *(const US8*)(Xb + (size_t)r * 1024 + col0 + 8);
  float x[16];
  const unsigned int ov[4] = {o16.x, o16.y, o16.z, o16.w};
#pragma unroll
  for (int j = 0; j < 4; ++j)
#pragma unroll
    for (int k = 0; k < 4; ++k)
      x[j * 4 + k] = fp8_to_f32((ov[j] >> (8 * k)) & 0xffu) * 0.0625f;
#pragma unroll
  for (int k = 0; k < 8; ++k) x[k] += bf16_to_f32(d0.s[k]);
#pragma unroll
  for (int k = 0; k < 8; ++k) x[8 + k] += bf16_to_f32(d1.s[k]);

  float sm = 0.f, sq = 0.f;
#pragma unroll
  for (int i = 0; i < 16; ++i) { sm += x[i]; sq += x[i] * x[i]; }
  sm = wave_sum(sm);
  sq = wave_sum(sq);
  const float mean = sm * (1.0f / 1024.0f);
  const float var = sq * (1.0f / 1024.0f) - mean * mean;
  const float rstd = rsqrtf(var + 1e-6f);
  float* op = out + (size_t)b * 786432 + (size_t)s * 1024 + col0;
#pragma unroll
  for (int j = 0; j < 4; ++j) {
    float4 g = *(const float4*)(gamma + col0 + j * 4);
    float4 be = *(const float4*)(beta + col0 + j * 4);
    float4 y;
    y.x = (x[j * 4 + 0] - mean) * rstd * g.x + be.x;
    y.y = (x[j * 4 + 1] - mean) * rstd * g.y + be.y;
    y.z = (x[j * 4 + 2] - mean) * rstd * g.z + be.z;
    y.w = (x[j * 4 + 3] - mean) * rstd * g.w + be.w;
    *(float4*)(op + j * 4) = y;
  }
}

extern "C" void kernel_launch(void* const* d_in, const int* in_sizes, int n_in,
                              void* d_out, int out_size, void* d_ws, size_t ws_size,
                              hipStream_t stream) {
  const float* data  = (const float*)d_in[0];
  const float* wq    = (const float*)d_in[1];
  const float* wk    = (const float*)d_in[2];
  const float* wv    = (const float*)d_in[3];
  const float* gamma = (const float*)d_in[4];
  const float* beta  = (const float*)d_in[5];
  float* out = (float*)d_out;
  char* ws = (char*)d_ws;
  if (ws_size < WS_NEED) return;

  unsigned short* Xb  = (unsigned short*)(ws + WS_XB);
  unsigned int*   Xf8 = (unsigned int*)(ws + WS_XF8);
  unsigned int*   Wf8 = (unsigned int*)(ws + WS_WF8);
  unsigned char*  Qf8 = (unsigned char*)(ws + WS_QF8);
  unsigned char*  Kf8 = (unsigned char*)(ws + WS_KF8);
  unsigned char*  Vt8 = (unsigned char*)(ws + WS_VT8);
  unsigned char*  S8  = (unsigned char*)(ws + WS_S8);
  unsigned char*  P8  = (unsigned char*)(ws + WS_P8);
  unsigned char*  O8  = (unsigned char*)(ws + WS_O8);

  cvt_all<<<9728, 256, 0, stream>>>(data, wq, wk, wv, Xb, Xf8, Wf8);
  qkv_128<<<3072, 256, 0, stream>>>((const unsigned char*)Xf8,
                                    (const unsigned char*)Wf8, Qf8, Kf8, Vt8);
  s_f8<<<dim3(4, 4, 32), 256, 0, stream>>>(Qf8, Kf8, S8);
  softmax_rows<<<4096, 256, 0, stream>>>(S8, out, P8);
  pv_f8<<<dim3(8, 4, 32), 256, 0, stream>>>(P8, Vt8, O8);
  ln_rows<<<4096, 256, 0, stream>>>(O8, Xb, gamma, beta, out);
}

// Round 18
// 163.594 us; speedup vs baseline: 1.0432x; 1.0115x over previous
//
#include <hip/hip_runtime.h>
#include <hip/hip_bf16.h>

// ModalAttention fused pipeline, MI355X (gfx950).
//
// Math: attn/|global_min| followed by L2-normalize cancels any positive
// per-tensor scale (incl. /sqrt(h)) -> softmax input = s_row/||s_row||_2,
// s = q.k. No global-min reduction needed.
//
// Round 18: single-barrier phase in the fp8 K=128 core. Old order
// {STAGE(t+1); vmcnt(8); bar; reads; MFMA; bar} needed the bottom
// barrier to protect the slot being staged. New order
// {vmcnt(0); bar; STAGE(t+1); reads; MFMA}: the top barrier alone
// guarantees (a) slot-t loads landed (per-wave vmcnt(0), issued a full
// phase earlier so drain is cheap) and (b) all waves' phase-(t-1) reads
// of the other slot are complete (program order before barrier arrival)
// before anyone overwrites it. Halves barrier count per phase across
// qkv/s/pv. Data math unchanged -> absmax bit-identical to round 17.

typedef float f32x4 __attribute__((ext_vector_type(4)));
typedef int i32x4v __attribute__((ext_vector_type(4)));
typedef int i32x8v __attribute__((ext_vector_type(8)));

struct alignas(16) US8 { unsigned short s[8]; };
struct alignas(8)  US4 { unsigned short s[4]; };

// ---------------- workspace layout (bytes, disjoint) ----------------
#define WS_XB   0ull                        // data bf16 [16384][1024] 33.55MB
#define WS_XF8  33554432ull                 // data fp8  [16384][1024] 16.78MB
#define WS_WF8  50331648ull                 // wq,wk,wv fp8 [3][1024][1024] 3.15MB
#define WS_QF8  53477376ull                 // Q fp8 [16384][1024] 16.78MB
#define WS_KF8  70254592ull                 // K fp8 [16384][1024] 16.78MB
#define WS_VT8  87031808ull                 // V^T fp8 [32][1024][512] 16.78MB
#define WS_S8   103809024ull                // S fp8 [16384][512] 8.39MB
#define WS_P8   112197632ull                // P fp8 (x256) [16384][512] 8.39MB
#define WS_O8   120586240ull                // O fp8 (x16) [16384][1024] 16.78MB
#define WS_NEED 137363456ull

__device__ __forceinline__ unsigned short f32_to_bf16(float f) {
  unsigned int u = __builtin_bit_cast(unsigned int, f);
  u += 0x7fffu + ((u >> 16) & 1u);            // round-to-nearest-even
  return (unsigned short)(u >> 16);
}
__device__ __forceinline__ float bf16_to_f32(unsigned short h) {
  return __builtin_bit_cast(float, (unsigned int)h << 16);
}

__device__ __forceinline__ void gload_lds16(const void* g, void* lds) {
  __builtin_amdgcn_global_load_lds(
      (const __attribute__((address_space(1))) unsigned int*)g,
      (__attribute__((address_space(3))) unsigned int*)lds, 16, 0, 0);
}

__device__ __forceinline__ float wave_sum(float v) {
#pragma unroll
  for (int off = 32; off > 0; off >>= 1) v += __shfl_xor(v, off);
  return v;
}
__device__ __forceinline__ float wave_max(float v) {
#pragma unroll
  for (int off = 32; off > 0; off >>= 1) v = fmaxf(v, __shfl_xor(v, off));
  return v;
}

__device__ __forceinline__ unsigned int pk_fp8x4(float a, float b, float c, float d) {
  unsigned int v = 0;
  v = __builtin_amdgcn_cvt_pk_fp8_f32(a, b, v, false);  // bytes 0,1
  v = __builtin_amdgcn_cvt_pk_fp8_f32(c, d, v, true);   // bytes 2,3
  return v;
}
__device__ __forceinline__ unsigned char f32_to_fp8(float v) {
  return (unsigned char)(__builtin_amdgcn_cvt_pk_fp8_f32(v, v, 0, false) & 0xffu);
}
// exact e4m3 -> f32 (normals AND subnormals)
__device__ __forceinline__ float fp8_to_f32(unsigned int b) {
  unsigned int u = ((b & 0x80u) << 24) | ((b & 0x7Fu) << 20);
  return __builtin_bit_cast(float, u) * 0x1p120f;
}

// ------- merged cast: data f32->bf16+fp8, weights f32->fp8, one launch -----
__global__ __launch_bounds__(256) void cvt_all(const float* __restrict__ data,
                                               const float* __restrict__ wq,
                                               const float* __restrict__ wk,
                                               const float* __restrict__ wv,
                                               unsigned short* __restrict__ Xb,
                                               unsigned int* __restrict__ Xf8,
                                               unsigned int* __restrict__ Wf8) {
  const int bid = blockIdx.x;
  if (bid < 8192) {                 // data: 2097152 groups of 8
    int i = bid * 256 + threadIdx.x;
    const float4* sp = (const float4*)(data + (size_t)i * 8);
    float4 a = sp[0], b = sp[1];
    US8 u;
    u.s[0] = f32_to_bf16(a.x); u.s[1] = f32_to_bf16(a.y);
    u.s[2] = f32_to_bf16(a.z); u.s[3] = f32_to_bf16(a.w);
    u.s[4] = f32_to_bf16(b.x); u.s[5] = f32_to_bf16(b.y);
    u.s[6] = f32_to_bf16(b.z); u.s[7] = f32_to_bf16(b.w);
    *(US8*)(Xb + (size_t)i * 8) = u;
    uint2 w;
    w.x = pk_fp8x4(a.x, a.y, a.z, a.w);
    w.y = pk_fp8x4(b.x, b.y, b.z, b.w);
    *(uint2*)(Xf8 + (size_t)i * 2) = w;
  } else {                          // weights: 3 x 512 blocks
    const int r = bid - 8192;
    const int z = r >> 9;
    const float* src = (z == 0) ? wq : (z == 1) ? wk : wv;
    int i = (r & 511) * 256 + threadIdx.x;
    const float4* sp = (const float4*)(src + (size_t)i * 8);
    float4 a = sp[0], b = sp[1];
    uint2 w;
    w.x = pk_fp8x4(a.x, a.y, a.z, a.w);
    w.y = pk_fp8x4(b.x, b.y, b.z, b.w);
    *(uint2*)(Wf8 + (size_t)z * 262144 + (size_t)i * 2) = w;
  }
}

// ==== fp8 K=128 GEMM core, 128x128 tile, 256 threads, 1 barrier/phase ====
template <int KB, int NKT>
__device__ __forceinline__ void f8c128(const char* __restrict__ Ag,
                                       const char* __restrict__ Bg,
                                       char* lds, f32x4 (&acc)[4][4]) {
  const int tid = threadIdx.x;
  const int w = tid >> 6, lane = tid & 63;
  const int wm = w >> 1, wn = w & 1;
  const int lr = lane & 15, lk4 = lane >> 4;

  const int sc = ((tid & 3) ^ ((tid >> 3) & 3)) * 16;
  const char* pA = Ag + (size_t)(tid >> 2) * KB + sc;
  const char* pB = Bg + (size_t)(tid >> 2) * KB + sc;
  const size_t R64 = (size_t)64 * KB;

  const int swz = (lr >> 1) & 3;
  const int c0 = (lk4 & 1) * 2;
  const int cb0 = ((c0) ^ swz) * 16;
  const int cb1 = ((c0 + 1) ^ swz) * 16;
  const int panA = (lk4 >> 1) * 8192;
  const int panB = 16384 + (lk4 >> 1) * 8192;
  const int rowA = (wm * 64 + lr) * 64;
  const int rowB = (wn * 64 + lr) * 64;

#define STAGE8(DD)                                                            \
  do {                                                                        \
    char* dd_ = (DD);                                                         \
    gload_lds16(pA,            dd_ + tid * 16);                               \
    gload_lds16(pA + R64,      dd_ + 4096 + tid * 16);                        \
    gload_lds16(pA + 64,       dd_ + 8192 + tid * 16);                        \
    gload_lds16(pA + R64 + 64, dd_ + 12288 + tid * 16);                       \
    gload_lds16(pB,            dd_ + 16384 + tid * 16);                       \
    gload_lds16(pB + R64,      dd_ + 20480 + tid * 16);                       \
    gload_lds16(pB + 64,       dd_ + 24576 + tid * 16);                       \
    gload_lds16(pB + R64 + 64, dd_ + 28672 + tid * 16);                       \
    pA += 128; pB += 128;                                                     \
  } while (0)

#define MK8(D, OFF)                                                           \
  do {                                                                        \
    i32x4v lo_ = *(const i32x4v*)(sp + (OFF) + cb0);                          \
    i32x4v hi_ = *(const i32x4v*)(sp + (OFF) + cb1);                          \
    D[0] = lo_[0]; D[1] = lo_[1]; D[2] = lo_[2]; D[3] = lo_[3];               \
    D[4] = hi_[0]; D[5] = hi_[1]; D[6] = hi_[2]; D[7] = hi_[3];               \
  } while (0)

#define MFMA128(ACC, AV, BV)                                                  \
  asm("v_mfma_f32_16x16x128_f8f6f4 %0, %1, %2, %0"                            \
      : "+a"(ACC) : "v"(AV), "v"(BV))

  STAGE8(lds);   // prologue: K-tile 0 -> slot 0 (8 loads outstanding)

#pragma unroll
  for (int t = 0; t < NKT; ++t) {
    const int slot = t & 1;
    // single sync point: own slot-t loads drained, then converge.
    asm volatile("s_waitcnt vmcnt(0)" ::: "memory");
    __builtin_amdgcn_s_barrier();
    __builtin_amdgcn_sched_barrier(0);
    // stage t+1 into the OTHER slot: safe — every wave's phase t-1 reads
    // of that slot precede its barrier arrival in program order.
    if (t + 1 < NKT) STAGE8(lds + (slot ^ 1) * 32768);
    const char* sp = lds + slot * 32768;
    i32x8v a0, a1, b0, b1, b2, b3;
    MK8(a0, panA + rowA);          MK8(a1, panA + rowA + 1024);
    MK8(b0, panB + rowB);          MK8(b1, panB + rowB + 1024);
    MK8(b2, panB + rowB + 2048);   MK8(b3, panB + rowB + 3072);
    __builtin_amdgcn_s_setprio(1);
    MFMA128(acc[0][0], a0, b0); MFMA128(acc[0][1], a0, b1);
    MFMA128(acc[0][2], a0, b2); MFMA128(acc[0][3], a0, b3);
    MFMA128(acc[1][0], a1, b0); MFMA128(acc[1][1], a1, b1);
    MFMA128(acc[1][2], a1, b2); MFMA128(acc[1][3], a1, b3);
    __builtin_amdgcn_s_setprio(0);
    i32x8v a2, a3;
    MK8(a2, panA + rowA + 2048);   MK8(a3, panA + rowA + 3072);
    __builtin_amdgcn_s_setprio(1);
    MFMA128(acc[2][0], a2, b0); MFMA128(acc[2][1], a2, b1);
    MFMA128(acc[2][2], a2, b2); MFMA128(acc[2][3], a2, b3);
    MFMA128(acc[3][0], a3, b0); MFMA128(acc[3][1], a3, b1);
    MFMA128(acc[3][2], a3, b2); MFMA128(acc[3][3], a3, b3);
    __builtin_amdgcn_s_setprio(0);
    __builtin_amdgcn_sched_barrier(0);
  }

#undef MFMA128
#undef MK8
#undef STAGE8
}

// ============ QKV: fp8 in/out (Q,K row-major; Vt transposed) ========
__global__ __launch_bounds__(256, 2) void qkv_128(
    const unsigned char* __restrict__ Xf8, const unsigned char* __restrict__ Wf8,
    unsigned char* __restrict__ Qf8, unsigned char* __restrict__ Kf8,
    unsigned char* __restrict__ Vt8) {
  __shared__ alignas(16) char smc[2][32768];
  const int bid = blockIdx.x;
  const int wg = (bid & 7) * 384 + (bid >> 3);   // bijective, 3072 % 8 == 0
  const int bm = wg / 24, bn = wg % 24;
  const char* Ag = (const char*)Xf8 + (size_t)bm * 128 * 1024;
  const char* Bg = (const char*)Wf8 + (size_t)bn * 128 * 1024;
  f32x4 acc[4][4] = {};
  f8c128<1024, 8>(Ag, Bg, &smc[0][0], acc);

  const int tid = threadIdx.x;
  const int w = tid >> 6, lane = tid & 63;
  const int wm = w >> 1, wn = w & 1;
  const int lr = lane & 15, lk4 = lane >> 4;
  const int cr = lk4 << 2;
  const int z = bn >> 3;                       // 0=Q 1=K 2=V
  const int gr0 = bm * 128 + wm * 64;
  const int gc0 = (bn & 7) * 128 + wn * 64;
  if (z < 2) {
    unsigned char* C = (z == 0) ? Qf8 : Kf8;
#pragma unroll
    for (int m = 0; m < 4; ++m)
#pragma unroll
      for (int n = 0; n < 4; ++n)
#pragma unroll
        for (int i = 0; i < 4; ++i)
          C[(size_t)(gr0 + m * 16 + cr + i) * 1024 + (gc0 + n * 16 + lr)] =
              f32_to_fp8(acc[m][n][i]);
  } else {
    // Vt8[b][d][t] = V[b*512+t][d]; 4 consecutive t -> one uint store
#pragma unroll
    for (int m = 0; m < 4; ++m) {
      const int gr = gr0 + m * 16 + cr;
      const int b = gr >> 9, tt = gr & 511;
#pragma unroll
      for (int n = 0; n < 4; ++n) {
        const int d = gc0 + n * 16 + lr;
        unsigned int u = pk_fp8x4(acc[m][n][0], acc[m][n][1],
                                  acc[m][n][2], acc[m][n][3]);
        *(unsigned int*)(Vt8 + ((size_t)b * 1024 + d) * 512 + tt) = u;
      }
    }
  }
}

// ============ S = Q K^T per batch (fp8 in, fp8 out) ============
__global__ __launch_bounds__(256, 2) void s_f8(
    const unsigned char* __restrict__ Qf8, const unsigned char* __restrict__ Kf8,
    unsigned char* __restrict__ S8) {
  __shared__ alignas(16) char smc[2][32768];
  const int bn = blockIdx.x, bm = blockIdx.y, b = blockIdx.z;
  const char* Ag = (const char*)Qf8 + ((size_t)b * 512 + bm * 128) * 1024;
  const char* Bg = (const char*)Kf8 + ((size_t)b * 512 + bn * 128) * 1024;
  f32x4 acc[4][4] = {};
  f8c128<1024, 8>(Ag, Bg, &smc[0][0], acc);

  const int tid = threadIdx.x;
  const int w = tid >> 6, lane = tid & 63;
  const int wm = w >> 1, wn = w & 1;
  const int lr = lane & 15, lk4 = lane >> 4;
  const int cr = lk4 << 2;
  unsigned char* Cp = S8 + (size_t)b * 262144;
  const int rbase = bm * 128 + wm * 64;
  const int cbase = bn * 128 + wn * 64;
#pragma unroll
  for (int m = 0; m < 4; ++m)
#pragma unroll
    for (int n = 0; n < 4; ++n)
#pragma unroll
      for (int i = 0; i < 4; ++i)
        Cp[(size_t)(rbase + m * 16 + cr + i) * 512 + (cbase + n * 16 + lr)] =
            f32_to_fp8(acc[m][n][i]);
}

// -------- row L2-normalize + softmax; attn f32 out + P fp8 (x256) --------
__global__ __launch_bounds__(256) void softmax_rows(const unsigned char* __restrict__ S8,
                                                    float* __restrict__ out,
                                                    unsigned char* __restrict__ P8) {
  const int w = threadIdx.x >> 6, lane = threadIdx.x & 63;
  const int r = blockIdx.x * 4 + w;          // global row 0..16383
  const int b = r >> 9, s = r & 511;
  uint2 v = *(const uint2*)(S8 + (size_t)r * 512 + lane * 8);
  float x[8];
#pragma unroll
  for (int i = 0; i < 4; ++i) x[i] = fp8_to_f32((v.x >> (8 * i)) & 0xffu);
#pragma unroll
  for (int i = 0; i < 4; ++i) x[4 + i] = fp8_to_f32((v.y >> (8 * i)) & 0xffu);
  float ss = 0.f;
#pragma unroll
  for (int i = 0; i < 8; ++i) ss += x[i] * x[i];
  ss = wave_sum(ss);
  const float inv = 1.0f / fmaxf(sqrtf(ss), 1e-12f);
  float mx = -1e30f;
#pragma unroll
  for (int i = 0; i < 8; ++i) { x[i] *= inv; mx = fmaxf(mx, x[i]); }
  mx = wave_max(mx);
  float se = 0.f;
#pragma unroll
  for (int i = 0; i < 8; ++i) { x[i] = __expf(x[i] - mx); se += x[i]; }
  se = wave_sum(se);
  const float rs = 1.0f / se;
#pragma unroll
  for (int i = 0; i < 8; ++i) x[i] *= rs;

  float* op = out + (size_t)b * 786432 + 524288 + (size_t)s * 512 + lane * 8;
  float4 o0 = {x[0], x[1], x[2], x[3]};
  float4 o1 = {x[4], x[5], x[6], x[7]};
  *(float4*)op = o0;
  *(float4*)(op + 4) = o1;
  // P stored x256 (attn ~2e-3 is on e4m3's subnormal floor; x256 -> normal)
  uint2 pw;
  pw.x = pk_fp8x4(x[0] * 256.f, x[1] * 256.f, x[2] * 256.f, x[3] * 256.f);
  pw.y = pk_fp8x4(x[4] * 256.f, x[5] * 256.f, x[6] * 256.f, x[7] * 256.f);
  *(uint2*)(P8 + (size_t)r * 512 + lane * 8) = pw;
}

// ====== O = P V via Vt (fp8 in, fp8 out x16: acc*(16/256) = acc/16) ======
__global__ __launch_bounds__(256, 2) void pv_f8(
    const unsigned char* __restrict__ P8, const unsigned char* __restrict__ Vt8,
    unsigned char* __restrict__ O8) {
  __shared__ alignas(16) char smc[2][32768];
  const int bn = blockIdx.x, bm = blockIdx.y, b = blockIdx.z;
  const char* Ag = (const char*)P8 + ((size_t)b * 512 + bm * 128) * 512;
  const char* Bg = (const char*)Vt8 + ((size_t)b * 1024 + bn * 128) * 512;
  f32x4 acc[4][4] = {};
  f8c128<512, 4>(Ag, Bg, &smc[0][0], acc);

  const int tid = threadIdx.x;
  const int w = tid >> 6, lane = tid & 63;
  const int wm = w >> 1, wn = w & 1;
  const int lr = lane & 15, lk4 = lane >> 4;
  const int cr = lk4 << 2;
  const int grow = b * 512 + bm * 128 + wm * 64;
  const int cbase = bn * 128 + wn * 64;
#pragma unroll
  for (int m = 0; m < 4; ++m)
#pragma unroll
    for (int n = 0; n < 4; ++n)
#pragma unroll
      for (int i = 0; i < 4; ++i)
        O8[(size_t)(grow + m * 16 + cr + i) * 1024 + (cbase + n * 16 + lr)] =
            f32_to_fp8(acc[m][n][i] * 0.0625f);   // /256 then x16
}

// ------- residual + LayerNorm; O fp8 (x16) + Xb bf16 -> out f32 -------
__global__ __launch_bounds__(256) void ln_rows(const unsigned char* __restrict__ O8,
                                               const unsigned short* __restrict__ Xb,
                                               const float* __restrict__ gamma,
                                               const float* __restrict__ beta,
                                               float* __restrict__ out) {
  const int w = threadIdx.x >> 6, lane = threadIdx.x & 63;
  const int r = blockIdx.x * 4 + w;
  const int b = r >> 9, s = r & 511;
  const int col0 = lane * 16;                // 16 consecutive cols per lane
  uint4 o16 = *(const uint4*)(O8 + (size_t)r * 1024 + col0);
  US8 d0 = *(const US8*)(Xb + (size_t)r * 1024 + col0);
  US8 d1 = *(const US8*)(Xb + (size_t)r * 1024 + col0 + 8);
  float x[16];
  const unsigned int ov[4] = {o16.x, o16.y, o16.z, o16.w};
#pragma unroll
  for (int j = 0; j < 4; ++j)
#pragma unroll
    for (int k = 0; k < 4; ++k)
      x[j * 4 + k] = fp8_to_f32((ov[j] >> (8 * k)) & 0xffu) * 0.0625f;
#pragma unroll
  for (int k = 0; k < 8; ++k) x[k] += bf16_to_f32(d0.s[k]);
#pragma unroll
  for (int k = 0; k < 8; ++k) x[8 + k] += bf16_to_f32(d1.s[k]);

  float sm = 0.f, sq = 0.f;
#pragma unroll
  for (int i = 0; i < 16; ++i) { sm += x[i]; sq += x[i] * x[i]; }
  sm = wave_sum(sm);
  sq = wave_sum(sq);
  const float mean = sm * (1.0f / 1024.0f);
  const float var = sq * (1.0f / 1024.0f) - mean * mean;
  const float rstd = rsqrtf(var + 1e-6f);
  float* op = out + (size_t)b * 786432 + (size_t)s * 1024 + col0;
#pragma unroll
  for (int j = 0; j < 4; ++j) {
    float4 g = *(const float4*)(gamma + col0 + j * 4);
    float4 be = *(const float4*)(beta + col0 + j * 4);
    float4 y;
    y.x = (x[j * 4 + 0] - mean) * rstd * g.x + be.x;
    y.y = (x[j * 4 + 1] - mean) * rstd * g.y + be.y;
    y.z = (x[j * 4 + 2] - mean) * rstd * g.z + be.z;
    y.w = (x[j * 4 + 3] - mean) * rstd * g.w + be.w;
    *(float4*)(op + j * 4) = y;
  }
}

extern "C" void kernel_launch(void* const* d_in, const int* in_sizes, int n_in,
                              void* d_out, int out_size, void* d_ws, size_t ws_size,
                              hipStream_t stream) {
  const float* data  = (const float*)d_in[0];
  const float* wq    = (const float*)d_in[1];
  const float* wk    = (const float*)d_in[2];
  const float* wv    = (const float*)d_in[3];
  const float* gamma = (const float*)d_in[4];
  const float* beta  = (const float*)d_in[5];
  float* out = (float*)d_out;
  char* ws = (char*)d_ws;
  if (ws_size < WS_NEED) return;

  unsigned short* Xb  = (unsigned short*)(ws + WS_XB);
  unsigned int*   Xf8 = (unsigned int*)(ws + WS_XF8);
  unsigned int*   Wf8 = (unsigned int*)(ws + WS_WF8);
  unsigned char*  Qf8 = (unsigned char*)(ws + WS_QF8);
  unsigned char*  Kf8 = (unsigned char*)(ws + WS_KF8);
  unsigned char*  Vt8 = (unsigned char*)(ws + WS_VT8);
  unsigned char*  S8  = (unsigned char*)(ws + WS_S8);
  unsigned char*  P8  = (unsigned char*)(ws + WS_P8);
  unsigned char*  O8  = (unsigned char*)(ws + WS_O8);

  cvt_all<<<9728, 256, 0, stream>>>(data, wq, wk, wv, Xb, Xf8, Wf8);
  qkv_128<<<3072, 256, 0, stream>>>((const unsigned char*)Xf8,
                                    (const unsigned char*)Wf8, Qf8, Kf8, Vt8);
  s_f8<<<dim3(4, 4, 32), 256, 0, stream>>>(Qf8, Kf8, S8);
  softmax_rows<<<4096, 256, 0, stream>>>(S8, out, P8);
  pv_f8<<<dim3(8, 4, 32), 256, 0, stream>>>(P8, Vt8, O8);
  ln_rows<<<4096, 256, 0, stream>>>(O8, Xb, gamma, beta, out);
}